// Round 5
// baseline (1618.823 us; speedup 1.0000x reference)
//
#include <hip/hip_runtime.h>
#include <cstddef>

#define SS 2048
#define BB 256
#define II 64
#define HH 128

typedef float v2f __attribute__((ext_vector_type(2)));

// DPP controls (compile-time only; no runtime-indexed register arrays anywhere)
#define DPP_XOR1 0xB1   // quad_perm [1,0,3,2]  : lane ^= 1
#define DPP_XOR2 0x4E   // quad_perm [2,3,0,1]  : lane ^= 2
#define DPP_HMIR 0x141  // row_half_mirror      : lane k <-> 7-k within 8-lane halves

template<int CTRL>
__device__ __forceinline__ float dpp_add(float v) {
  union { float f; int i; } u, r;
  u.f = v;
  r.i = __builtin_amdgcn_update_dpp(0, u.i, CTRL, 0xF, 0xF, true);
  return v + r.f;
}

__device__ __forceinline__ float fast_rcp(float v) {
  return __builtin_amdgcn_rcpf(v);  // v_rcp_f32, ~1 ulp
}

// packed fp32 FMA: 2 MACs per instruction (VOP3P, gfx90a+)
__device__ __forceinline__ void pk_fma(v2f& acc, v2f a, v2f b) {
  asm("v_pk_fma_f32 %0, %1, %2, %0" : "+v"(acc) : "v"(a), "v"(b));
}

// Opaque identity: blocks rematerialization of the loaded weights.
#define KEEP(x) asm volatile("" : "+v"(x))

// One workgroup per batch element; 512 threads = 8 waves; grid 256 = 1 block/CU.
// amdgpu_waves_per_eu(2,2): exactly 2 waves/SIMD -> 256-VGPR budget, so the
// 72 weight pairs live in arch VGPRs (R4: allocator kept VGPR_Count=100 and
// spilled weights to AGPRs -> ~144 v_accvgpr_read per thread per step).
__global__ __launch_bounds__(512)
__attribute__((amdgpu_waves_per_eu(2, 2)))
void gru_fused(
    const float* __restrict__ x,        // [B,S,I]
    const int*   __restrict__ mask,     // [B,S,I]
    const float* __restrict__ x_mean,   // [I]
    const float* __restrict__ w_ih,     // [3H,I]
    const float* __restrict__ w_hh,     // [3H,H]
    const float* __restrict__ b_ih,     // [3H]
    const float* __restrict__ b_hh,     // [3H]
    const float* __restrict__ bn_gamma, // [H]
    const float* __restrict__ bn_beta,  // [H]
    const float* __restrict__ bn_mean,  // [H]
    const float* __restrict__ bn_var,   // [H]
    const float* __restrict__ fc_w,     // [1,H]
    const float* __restrict__ fc_b,     // [1]
    float* __restrict__ out)            // [B,1]
{
  const int b     = blockIdx.x;
  const int tid   = threadIdx.x;
  const int slice = tid & 7;   // K-slice: h[slice*16..+15], xi[slice*8..+7]
  const int idx   = tid >> 3;  // 0..63; owns hidden {idx, idx+64}
  const int hx0   = idx;
  const int hx1   = idx + 64;

  __shared__ __align__(16) float xi_lds[2][II];
  // transposed h store: h[k] lives at word (k&15)*8 + (k>>4).
  // read pattern j*8+slice -> 8 banks, 8-lane same-address broadcast: conflict-free.
  __shared__ float h_tr[2][HH];
  __shared__ float h_fin[HH];

  // ---- weights -> register pairs (once); pinned via KEEP ----
  v2f whp[6][8];  // [u*3+g][pair], g in {r,z,n}, u in {hx0,hx1}
  v2f wip[6][4];
  #pragma unroll
  for (int u = 0; u < 2; ++u) {
    const int hh = u ? hx1 : hx0;
    #pragma unroll
    for (int g = 0; g < 3; ++g) {
      const float* pr = w_hh + (size_t)(g * HH + hh) * HH + slice * 16;
      #pragma unroll
      for (int q = 0; q < 4; ++q) {
        float4 v = *reinterpret_cast<const float4*>(pr + q * 4);
        whp[u*3+g][q*2+0] = v2f{v.x, v.y};
        whp[u*3+g][q*2+1] = v2f{v.z, v.w};
      }
      const float* pi = w_ih + (size_t)(g * HH + hh) * II + slice * 8;
      #pragma unroll
      for (int q = 0; q < 2; ++q) {
        float4 v = *reinterpret_cast<const float4*>(pi + q * 4);
        wip[u*3+g][q*2+0] = v2f{v.x, v.y};
        wip[u*3+g][q*2+1] = v2f{v.z, v.w};
      }
    }
  }
  #pragma unroll
  for (int r = 0; r < 6; ++r) {
    #pragma unroll
    for (int j = 0; j < 8; ++j) KEEP(whp[r][j]);
    #pragma unroll
    for (int i2 = 0; i2 < 4; ++i2) KEEP(wip[r][i2]);
  }

  // biases folded into slice 0's partial sums (butterfly gives all lanes the total)
  float bR[2], bZ[2], bNX[2], bNH[2];
  const bool lead = (slice == 0);
  #pragma unroll
  for (int u = 0; u < 2; ++u) {
    const int hh = u ? hx1 : hx0;
    bR[u]  = lead ? (b_ih[hh]      + b_hh[hh])      : 0.f;
    bZ[u]  = lead ? (b_ih[HH+hh]   + b_hh[HH+hh])   : 0.f;
    bNX[u] = lead ?  b_ih[2*HH+hh]                  : 0.f;
    bNH[u] = lead ?  b_hh[2*HH+hh]                  : 0.f;
    KEEP(bR[u]); KEEP(bZ[u]); KEEP(bNX[u]); KEEP(bNH[u]);
  }

  // ---- prologue: LOCF state + first prefetch ----
  const size_t xbase = (size_t)b * SS * II;
  float last = 0.f, xn = 0.f;
  int   mn = 0;
  const float* xq = x + xbase + II + tid;
  const int*   mq = mask + xbase + II + tid;
  if (tid < II) {
    last = x_mean[tid];
    xn   = x[xbase + tid];
    mn   = mask[xbase + tid];
  }
  float hcA = 0.f, hcB = 0.f;  // h[t-1][hx0], h[t-1][hx1] carried in-register

  for (int t = 0; t < SS; ++t) {
    const int p = t & 1;
    // publish xi[t] and h[t-1] into buffer p
    if (tid < II) {
      last = (mn > 0) ? xn : last;
      xi_lds[p][tid] = last;
    }
    if (lead) {
      const int tw = (idx & 15) * 8 + (idx >> 4);
      h_tr[p][tw]     = hcA;   // T(idx)
      h_tr[p][tw + 4] = hcB;   // T(idx+64) = T(idx)+4
    }
    __syncthreads();  // one barrier/step; double-buffer covers WAR

    // prefetch t+1 (global, hides under compute)
    if (tid < II && t + 1 < SS) {
      xn = *xq;  mn = *mq;
      xq += II;  mq += II;
    }

    // xi pairs straight from float4; h pairs from 2x b32 32B apart (ds_read2_b32)
    v2f xvp[4], hvp[8];
    #pragma unroll
    for (int q = 0; q < 2; ++q) {
      float4 v = *reinterpret_cast<const float4*>(&xi_lds[p][slice * 8 + q * 4]);
      xvp[q*2+0] = v2f{v.x, v.y};
      xvp[q*2+1] = v2f{v.z, v.w};
    }
    #pragma unroll
    for (int q = 0; q < 8; ++q) {
      hvp[q] = v2f{h_tr[p][(2*q) * 8 + slice], h_tr[p][(2*q+1) * 8 + slice]};
    }

    float sR[2], sZ[2], sNX[2], sNH[2];
    #pragma unroll
    for (int u = 0; u < 2; ++u) {
      v2f aR = {0.f, 0.f}, aZ = {0.f, 0.f}, aNH = {0.f, 0.f}, aNX = {0.f, 0.f};
      #pragma unroll
      for (int q = 0; q < 8; ++q) {
        pk_fma(aR,  whp[u*3+0][q], hvp[q]);
        pk_fma(aZ,  whp[u*3+1][q], hvp[q]);
        pk_fma(aNH, whp[u*3+2][q], hvp[q]);
      }
      #pragma unroll
      for (int q = 0; q < 4; ++q) {
        pk_fma(aR,  wip[u*3+0][q], xvp[q]);
        pk_fma(aZ,  wip[u*3+1][q], xvp[q]);
        pk_fma(aNX, wip[u*3+2][q], xvp[q]);
      }
      sR[u]  = aR.x  + aR.y  + bR[u];
      sZ[u]  = aZ.x  + aZ.y  + bZ[u];
      sNX[u] = aNX.x + aNX.y + bNX[u];
      sNH[u] = aNH.x + aNH.y + bNH[u];
    }

    // pure-VALU butterfly over 8 slices
    #pragma unroll
    for (int u = 0; u < 2; ++u) {
      sR[u]  = dpp_add<DPP_XOR1>(sR[u]);
      sZ[u]  = dpp_add<DPP_XOR1>(sZ[u]);
      sNX[u] = dpp_add<DPP_XOR1>(sNX[u]);
      sNH[u] = dpp_add<DPP_XOR1>(sNH[u]);
    }
    #pragma unroll
    for (int u = 0; u < 2; ++u) {
      sR[u]  = dpp_add<DPP_XOR2>(sR[u]);
      sZ[u]  = dpp_add<DPP_XOR2>(sZ[u]);
      sNX[u] = dpp_add<DPP_XOR2>(sNX[u]);
      sNH[u] = dpp_add<DPP_XOR2>(sNH[u]);
    }
    #pragma unroll
    for (int u = 0; u < 2; ++u) {
      sR[u]  = dpp_add<DPP_HMIR>(sR[u]);
      sZ[u]  = dpp_add<DPP_HMIR>(sZ[u]);
      sNX[u] = dpp_add<DPP_HMIR>(sNX[u]);
      sNH[u] = dpp_add<DPP_HMIR>(sNH[u]);
    }

    // gates: rcp/exp based; no clamp needed (exp->inf => rcp->0 => n=+/-1, no NaN)
    {
      float r0 = fast_rcp(1.f + __expf(-sR[0]));
      float z0 = fast_rcp(1.f + __expf(-sZ[0]));
      float a0 = sNX[0] + r0 * sNH[0];
      float n0 = 1.f - 2.f * fast_rcp(__expf(2.f * a0) + 1.f);
      hcA = n0 + z0 * (hcA - n0);

      float r1 = fast_rcp(1.f + __expf(-sR[1]));
      float z1 = fast_rcp(1.f + __expf(-sZ[1]));
      float a1 = sNX[1] + r1 * sNH[1];
      float n1 = 1.f - 2.f * fast_rcp(__expf(2.f * a1) + 1.f);
      hcB = n1 + z1 * (hcB - n1);
    }
    // next step writes buffer p^1: no second barrier
  }

  // publish final h
  if (lead) { h_fin[hx0] = hcA; h_fin[hx1] = hcB; }
  __syncthreads();

  // BN (eval) + FC, reduced by wave 0
  if (tid < 64) {
    float pacc = 0.f;
    #pragma unroll
    for (int q = 0; q < 2; ++q) {
      const int k = tid + q * 64;
      const float hv2 = h_fin[k];
      const float nrm = (hv2 - bn_mean[k]) * rsqrtf(bn_var[k] + 1e-5f) * bn_gamma[k] + bn_beta[k];
      pacc += nrm * fc_w[k];
    }
    #pragma unroll
    for (int off = 32; off > 0; off >>= 1) pacc += __shfl_down(pacc, off);
    if (tid == 0) out[b] = pacc + fc_b[0];
  }
}

extern "C" void kernel_launch(void* const* d_in, const int* in_sizes, int n_in,
                              void* d_out, int out_size, void* d_ws, size_t ws_size,
                              hipStream_t stream) {
  const float* x        = (const float*)d_in[0];
  const int*   mask     = (const int*)  d_in[1];
  // d_in[2] = delta (unused by reference forward)
  const float* x_mean   = (const float*)d_in[3];
  const float* w_ih     = (const float*)d_in[4];
  const float* w_hh     = (const float*)d_in[5];
  const float* b_ih     = (const float*)d_in[6];
  const float* b_hh     = (const float*)d_in[7];
  const float* bn_gamma = (const float*)d_in[8];
  const float* bn_beta  = (const float*)d_in[9];
  const float* bn_mean  = (const float*)d_in[10];
  const float* bn_var   = (const float*)d_in[11];
  const float* fc_w     = (const float*)d_in[12];
  const float* fc_b     = (const float*)d_in[13];
  float* out = (float*)d_out;

  gru_fused<<<dim3(BB), dim3(512), 0, stream>>>(
      x, mask, x_mean, w_ih, w_hh, b_ih, b_hh,
      bn_gamma, bn_beta, bn_mean, bn_var, fc_w, fc_b, out);
}

// Round 7
// 1532.219 us; speedup vs baseline: 1.0565x; 1.0565x over previous
//
#include <hip/hip_runtime.h>
#include <cstddef>

#define SS 2048
#define BB 256
#define II 64
#define HH 128

typedef _Float16 h2 __attribute__((ext_vector_type(2)));
typedef __fp16   fp16v2 __attribute__((ext_vector_type(2)));

// bit-identical cast: cvt_pkrtz returns __fp16x2, our storage type is _Float16x2
__device__ __forceinline__ h2 pack_f16(float a, float b) {
  union { fp16v2 raw; h2 out; } cv;
  cv.raw = __builtin_amdgcn_cvt_pkrtz(a, b);
  return cv.out;
}

// DPP controls (compile-time only)
#define DPP_XOR1 0xB1   // quad_perm [1,0,3,2]  : lane ^= 1
#define DPP_XOR2 0x4E   // quad_perm [2,3,0,1]  : lane ^= 2
#define DPP_HMIR 0x141  // row_half_mirror      : lane k <-> 7-k within 8-lane halves

template<int CTRL>
__device__ __forceinline__ float dpp_add(float v) {
  union { float f; int i; } u, r;
  u.f = v;
  r.i = __builtin_amdgcn_update_dpp(0, u.i, CTRL, 0xF, 0xF, true);
  return v + r.f;
}

__device__ __forceinline__ float fast_rcp(float v) {
  return __builtin_amdgcn_rcpf(v);
}

// v_dot2_f32_f16: acc += a.x*b.x + a.y*b.y (f16 inputs, f32 accumulate)
__device__ __forceinline__ float dot2(h2 a, h2 b, float acc) {
  float d = acc;
  asm("v_dot2_f32_f16 %0, %1, %2, %0" : "+v"(d) : "v"(a), "v"(b));
  return d;
}

// Opaque identity: blocks rematerialization of loaded weights.
#define KEEP(x) asm volatile("" : "+v"(x))

// One workgroup per batch element; 1024 threads = 16 waves; grid 256 = 1 block/CU.
// hu = tid>>3 owns ONE hidden unit (its r,z,n rows); slice = tid&7 is the
// K-slice (16 h-cols / 8 xi-cols). Per-thread live set ~85 regs -> fits the
// allocator's preferred budget, ending the R4/R5 AGPR-shuffle tax (VGPR stuck
// at 104 with 144 f32 weights; f16 pairs = 36 regs of weights).
__global__ __launch_bounds__(1024) void gru_fused(
    const float* __restrict__ x,        // [B,S,I]
    const int*   __restrict__ mask,     // [B,S,I]
    const float* __restrict__ x_mean,   // [I]
    const float* __restrict__ w_ih,     // [3H,I]
    const float* __restrict__ w_hh,     // [3H,H]
    const float* __restrict__ b_ih,     // [3H]
    const float* __restrict__ b_hh,     // [3H]
    const float* __restrict__ bn_gamma, // [H]
    const float* __restrict__ bn_beta,  // [H]
    const float* __restrict__ bn_mean,  // [H]
    const float* __restrict__ bn_var,   // [H]
    const float* __restrict__ fc_w,     // [1,H]
    const float* __restrict__ fc_b,     // [1]
    float* __restrict__ out)            // [B,1]
{
  const int b     = blockIdx.x;
  const int tid   = threadIdx.x;
  const int slice = tid & 7;    // K-slice
  const int hu    = tid >> 3;   // hidden unit 0..127
  const bool lead = (slice == 0);

  // h stored as f16 pairs, transposed: pair pj=(slice*8+q) lives at word q*8+slice.
  // element k -> halfword ((((k>>1)&7)*8 + (k>>4))<<1) + (k&1)
  __shared__ h2 hbuf[2][64];
  __shared__ h2 xi_l[2][32];   // xi pair i2 at word i2
  __shared__ float h_fin[HH];

  // ---- weights -> f16 pair registers (once) ----
  h2 wh[3][8];  // [g][pair], g in {r,z,n}; cols slice*16 + 2q,2q+1
  h2 wi[3][4];  // cols slice*8 + 2q,2q+1
  #pragma unroll
  for (int g = 0; g < 3; ++g) {
    const float* pr = w_hh + (size_t)(g * HH + hu) * HH + slice * 16;
    #pragma unroll
    for (int q = 0; q < 4; ++q) {
      float4 v = *reinterpret_cast<const float4*>(pr + q * 4);
      wh[g][q*2+0] = pack_f16(v.x, v.y);
      wh[g][q*2+1] = pack_f16(v.z, v.w);
    }
    const float* pi = w_ih + (size_t)(g * HH + hu) * II + slice * 8;
    #pragma unroll
    for (int q = 0; q < 2; ++q) {
      float4 v = *reinterpret_cast<const float4*>(pi + q * 4);
      wi[g][q*2+0] = pack_f16(v.x, v.y);
      wi[g][q*2+1] = pack_f16(v.z, v.w);
    }
  }
  #pragma unroll
  for (int g = 0; g < 3; ++g) {
    #pragma unroll
    for (int j = 0; j < 8; ++j) KEEP(wh[g][j]);
    #pragma unroll
    for (int j = 0; j < 4; ++j) KEEP(wi[g][j]);
  }

  // biases (lead slice only; butterfly spreads the total to all slices)
  float bR = 0.f, bZ = 0.f, bNX = 0.f, bNH = 0.f;
  if (lead) {
    bR  = b_ih[hu]        + b_hh[hu];
    bZ  = b_ih[HH + hu]   + b_hh[HH + hu];
    bNX = b_ih[2*HH + hu];
    bNH = b_hh[2*HH + hu];
  }

  // h-writer slot (halfword index), loop-invariant
  const int hw = ((((hu >> 1) & 7) * 8 + (hu >> 4)) << 1) + (hu & 1);
  _Float16* hp = reinterpret_cast<_Float16*>(&hbuf[0][0]);

  // ---- prologue: LOCF state (32 writer threads x 2 elems) + first prefetch ----
  const size_t xbase = (size_t)b * SS * II;
  float last0 = 0.f, last1 = 0.f;
  float2 xn = {0.f, 0.f};
  int2   mn = {0, 0};
  const float2* xq = reinterpret_cast<const float2*>(x + xbase + II) + tid;
  const int2*   mq = reinterpret_cast<const int2*>(mask + xbase + II) + tid;
  if (tid < 32) {
    float2 xm0 = reinterpret_cast<const float2*>(x_mean)[tid];
    last0 = xm0.x; last1 = xm0.y;
    xn = reinterpret_cast<const float2*>(x + xbase)[tid];
    mn = reinterpret_cast<const int2*>(mask + xbase)[tid];
  }
  float hc = 0.f;  // h[t-1][hu], full f32 carried in-register

  for (int t = 0; t < SS; ++t) {
    const int p = t & 1;
    // publish xi[t] (packed f16) and h[t-1] (f16 halfword) into buffer p
    if (tid < 32) {
      last0 = (mn.x > 0) ? xn.x : last0;
      last1 = (mn.y > 0) ? xn.y : last1;
      xi_l[p][tid] = pack_f16(last0, last1);
    }
    if (lead) hp[p * 128 + hw] = (_Float16)hc;
    __syncthreads();  // one barrier/step; double-buffer covers WAR

    // prefetch t+1
    if (tid < 32 && t + 1 < SS) {
      xn = *xq;  mn = *mq;
      xq += 32;  mq += 32;
    }

    // fragment reads: conflict-free (8 banks x broadcast / 32 distinct banks)
    h2 hv[8], xv[4];
    #pragma unroll
    for (int q = 0; q < 8; ++q) hv[q] = hbuf[p][q * 8 + slice];
    #pragma unroll
    for (int q = 0; q < 4; ++q) xv[q] = xi_l[p][slice * 4 + q];

    // dot2 GEMV partials (bias folded into lead's init)
    float aR = bR, aZ = bZ, aNX = bNX, aNH = bNH;
    #pragma unroll
    for (int q = 0; q < 8; ++q) {
      aR  = dot2(wh[0][q], hv[q], aR);
      aZ  = dot2(wh[1][q], hv[q], aZ);
      aNH = dot2(wh[2][q], hv[q], aNH);
    }
    #pragma unroll
    for (int q = 0; q < 4; ++q) {
      aR  = dot2(wi[0][q], xv[q], aR);
      aZ  = dot2(wi[1][q], xv[q], aZ);
      aNX = dot2(wi[2][q], xv[q], aNX);
    }

    // pure-VALU butterfly over the 8 slices
    aR = dpp_add<DPP_XOR1>(aR); aZ = dpp_add<DPP_XOR1>(aZ);
    aNX = dpp_add<DPP_XOR1>(aNX); aNH = dpp_add<DPP_XOR1>(aNH);
    aR = dpp_add<DPP_XOR2>(aR); aZ = dpp_add<DPP_XOR2>(aZ);
    aNX = dpp_add<DPP_XOR2>(aNX); aNH = dpp_add<DPP_XOR2>(aNH);
    aR = dpp_add<DPP_HMIR>(aR); aZ = dpp_add<DPP_HMIR>(aZ);
    aNX = dpp_add<DPP_HMIR>(aNX); aNH = dpp_add<DPP_HMIR>(aNH);

    // gates (redundant across 8 slices; slice 0 publishes)
    {
      float r = fast_rcp(1.f + __expf(-aR));
      float z = fast_rcp(1.f + __expf(-aZ));
      float a = aNX + r * aNH;
      float n = 1.f - 2.f * fast_rcp(__expf(2.f * a) + 1.f);
      hc = n + z * (hc - n);
    }
    // next step writes buffer p^1: no second barrier
  }

  // publish final h (f32)
  if (lead) h_fin[hu] = hc;
  __syncthreads();

  // BN (eval) + FC, reduced by wave 0
  if (tid < 64) {
    float pacc = 0.f;
    #pragma unroll
    for (int q = 0; q < 2; ++q) {
      const int k = tid + q * 64;
      const float hv2 = h_fin[k];
      const float nrm = (hv2 - bn_mean[k]) * rsqrtf(bn_var[k] + 1e-5f) * bn_gamma[k] + bn_beta[k];
      pacc += nrm * fc_w[k];
    }
    #pragma unroll
    for (int off = 32; off > 0; off >>= 1) pacc += __shfl_down(pacc, off);
    if (tid == 0) out[b] = pacc + fc_b[0];
  }
}

extern "C" void kernel_launch(void* const* d_in, const int* in_sizes, int n_in,
                              void* d_out, int out_size, void* d_ws, size_t ws_size,
                              hipStream_t stream) {
  const float* x        = (const float*)d_in[0];
  const int*   mask     = (const int*)  d_in[1];
  // d_in[2] = delta (unused by reference forward)
  const float* x_mean   = (const float*)d_in[3];
  const float* w_ih     = (const float*)d_in[4];
  const float* w_hh     = (const float*)d_in[5];
  const float* b_ih     = (const float*)d_in[6];
  const float* b_hh     = (const float*)d_in[7];
  const float* bn_gamma = (const float*)d_in[8];
  const float* bn_beta  = (const float*)d_in[9];
  const float* bn_mean  = (const float*)d_in[10];
  const float* bn_var   = (const float*)d_in[11];
  const float* fc_w     = (const float*)d_in[12];
  const float* fc_b     = (const float*)d_in[13];
  float* out = (float*)d_out;

  gru_fused<<<dim3(BB), dim3(1024), 0, stream>>>(
      x, mask, x_mean, w_ih, w_hh, b_ih, b_hh,
      bn_gamma, bn_beta, bn_mean, bn_var, fc_w, fc_b, out);
}

// Round 8
// 1353.678 us; speedup vs baseline: 1.1959x; 1.1319x over previous
//
#include <hip/hip_runtime.h>
#include <cstddef>

#define SS 2048
#define BB 256
#define II 64
#define HH 128

typedef _Float16 h8 __attribute__((ext_vector_type(8)));
typedef _Float16 h2 __attribute__((ext_vector_type(2)));
typedef float    f4 __attribute__((ext_vector_type(4)));
typedef __fp16   fp16v2 __attribute__((ext_vector_type(2)));

__device__ __forceinline__ h2 pack_f16(float a, float b) {
  union { fp16v2 raw; h2 out; } cv;
  cv.raw = __builtin_amdgcn_cvt_pkrtz(a, b);
  return cv.out;
}
__device__ __forceinline__ float fast_rcp(float v) {
  return __builtin_amdgcn_rcpf(v);
}
// blocks rematerialization of once-loaded values (spill-to-AGPR is fine now:
// MFMA reads A/B operands straight from AGPRs on gfx950's unified file)
#define KEEP(x) asm volatile("" : "+v"(x))

__device__ __forceinline__ f4 mfma16(h8 a, h8 b, f4 c) {
  return __builtin_amdgcn_mfma_f32_16x16x32_f16(a, b, c, 0, 0, 0);
}

// One workgroup per batch element; 512 threads = 8 waves; grid 256 = 1 block/CU.
// Wave wv owns hidden units [16wv, 16wv+16) via three W row-tiles (r,z,n).
// MFMA scheme: A = W-tile [16 rows x 32 k] (frags persistent, AGPR-friendly),
// B = h (or xi) broadcast into all 16 cols -> B-frag = 8 contiguous f16 from
// LDS. C layout (m89-verified): lane(l) reg q = D[(l>>4)*4+q][l&15] ->
// lane holds gh for hu = 16wv + (l>>4)*4 + q, replicated over the 16 cols.
__global__ __launch_bounds__(512) void gru_fused(
    const float* __restrict__ x,        // [B,S,I]
    const int*   __restrict__ mask,     // [B,S,I]
    const float* __restrict__ x_mean,   // [I]
    const float* __restrict__ w_ih,     // [3H,I]
    const float* __restrict__ w_hh,     // [3H,H]
    const float* __restrict__ b_ih,     // [3H]
    const float* __restrict__ b_hh,     // [3H]
    const float* __restrict__ bn_gamma, // [H]
    const float* __restrict__ bn_beta,  // [H]
    const float* __restrict__ bn_mean,  // [H]
    const float* __restrict__ bn_var,   // [H]
    const float* __restrict__ fc_w,     // [1,H]
    const float* __restrict__ fc_b,     // [1]
    float* __restrict__ out)            // [B,1]
{
  const int b   = blockIdx.x;
  const int tid = threadIdx.x;
  const int wv  = tid >> 6;   // wave 0..7
  const int l   = tid & 63;
  const int col = l & 15;     // A row / C col
  const int grp = l >> 4;     // k-group

  __shared__ __align__(16) _Float16 h_lds[2][HH];
  __shared__ __align__(16) _Float16 xi_lds[2][II];
  __shared__ float h_fin[HH];

  // ---- A-fragments (weights), loaded once ----
  // frag elem j = W[row][ kt*32 + grp*8 + j ]
  h8 whA[3][4];  // g in {r,z,n} x 4 k-tiles (K=128)
  h8 wiA[3][2];  // g x 2 k-tiles (K=64)
  #pragma unroll
  for (int g = 0; g < 3; ++g) {
    const int row = g * HH + wv * 16 + col;
    #pragma unroll
    for (int kt = 0; kt < 4; ++kt) {
      const float* pw = w_hh + (size_t)row * HH + kt * 32 + grp * 8;
      float4 va = *reinterpret_cast<const float4*>(pw);
      float4 vb = *reinterpret_cast<const float4*>(pw + 4);
      h8 f;
      f[0]=(_Float16)va.x; f[1]=(_Float16)va.y; f[2]=(_Float16)va.z; f[3]=(_Float16)va.w;
      f[4]=(_Float16)vb.x; f[5]=(_Float16)vb.y; f[6]=(_Float16)vb.z; f[7]=(_Float16)vb.w;
      whA[g][kt] = f;
    }
    #pragma unroll
    for (int kt = 0; kt < 2; ++kt) {
      const float* pw = w_ih + (size_t)row * II + kt * 32 + grp * 8;
      float4 va = *reinterpret_cast<const float4*>(pw);
      float4 vb = *reinterpret_cast<const float4*>(pw + 4);
      h8 f;
      f[0]=(_Float16)va.x; f[1]=(_Float16)va.y; f[2]=(_Float16)va.z; f[3]=(_Float16)va.w;
      f[4]=(_Float16)vb.x; f[5]=(_Float16)vb.y; f[6]=(_Float16)vb.z; f[7]=(_Float16)vb.w;
      wiA[g][kt] = f;
    }
  }
  #pragma unroll
  for (int g = 0; g < 3; ++g) {
    #pragma unroll
    for (int kt = 0; kt < 4; ++kt) KEEP(whA[g][kt]);
    #pragma unroll
    for (int kt = 0; kt < 2; ++kt) KEEP(wiA[g][kt]);
  }

  // ---- bias C-init fragments (per-step accumulate starts from these) ----
  f4 bRf, bZf, bNXf, bNHf;
  #pragma unroll
  for (int q = 0; q < 4; ++q) {
    const int hu = wv * 16 + grp * 4 + q;
    bRf[q]  = b_ih[hu]        + b_hh[hu];
    bZf[q]  = b_ih[HH + hu]   + b_hh[HH + hu];
    bNXf[q] = b_ih[2*HH + hu];
    bNHf[q] = b_hh[2*HH + hu];
  }
  KEEP(bRf); KEEP(bZf); KEEP(bNXf); KEEP(bNHf);

  // ---- prologue: LOCF state (32 writer threads x 2 channels) + prefetch ----
  const size_t xbase = (size_t)b * SS * II;
  float last0 = 0.f, last1 = 0.f;
  float2 xn = {0.f, 0.f};
  int2   mn = {0, 0};
  const float2* xq = reinterpret_cast<const float2*>(x + xbase + II) + tid;
  const int2*   mq = reinterpret_cast<const int2*>(mask + xbase + II) + tid;
  if (tid < 32) {
    float2 xm0 = reinterpret_cast<const float2*>(x_mean)[tid];
    last0 = xm0.x; last1 = xm0.y;
    xn = reinterpret_cast<const float2*>(x + xbase)[tid];
    mn = reinterpret_cast<const int2*>(mask + xbase)[tid];
  }
  float ho0 = 0.f, ho1 = 0.f, ho2 = 0.f, ho3 = 0.f;  // h[t-1] for this lane's 4 hu

  for (int t = 0; t < SS; ++t) {
    const int p = t & 1;
    // publish xi[t] and h[t-1] into buffer p
    if (tid < 32) {
      last0 = (mn.x > 0) ? xn.x : last0;
      last1 = (mn.y > 0) ? xn.y : last1;
      reinterpret_cast<h2*>(&xi_lds[p][0])[tid] = pack_f16(last0, last1);
    }
    if (col == 0) {
      h2* d = reinterpret_cast<h2*>(&h_lds[p][wv * 16 + grp * 4]);
      d[0] = pack_f16(ho0, ho1);
      d[1] = pack_f16(ho2, ho3);
    }
    __syncthreads();  // one barrier/step; double-buffer covers WAR

    // prefetch t+1
    if (tid < 32 && t + 1 < SS) {
      xn = *xq;  mn = *mq;
      xq += 32;  mq += 32;
    }

    // B-fragments: 8 contiguous f16 at k = kt*32 + grp*8 (16B-aligned,
    // 4 distinct addresses/wave in distinct bank quads, 16-lane broadcast)
    h8 hB[4], xB[2];
    #pragma unroll
    for (int kt = 0; kt < 4; ++kt)
      hB[kt] = *reinterpret_cast<const h8*>(&h_lds[p][kt * 32 + grp * 8]);
    #pragma unroll
    for (int kt = 0; kt < 2; ++kt)
      xB[kt] = *reinterpret_cast<const h8*>(&xi_lds[p][kt * 32 + grp * 8]);

    // 18 MFMAs: r,z get hh(4)+ih(2); n split into NH (hh, 4) and NX (ih, 2)
    f4 aR = bRf, aZ = bZf, aNH = bNHf, aNX = bNXf;
    #pragma unroll
    for (int kt = 0; kt < 4; ++kt) {
      aR  = mfma16(whA[0][kt], hB[kt], aR);
      aZ  = mfma16(whA[1][kt], hB[kt], aZ);
      aNH = mfma16(whA[2][kt], hB[kt], aNH);
    }
    #pragma unroll
    for (int kt = 0; kt < 2; ++kt) {
      aR  = mfma16(wiA[0][kt], xB[kt], aR);
      aZ  = mfma16(wiA[1][kt], xB[kt], aZ);
      aNX = mfma16(wiA[2][kt], xB[kt], aNX);
    }

    // gates: lane-local (no cross-lane reduce needed)
    {
      float r0 = fast_rcp(1.f + __expf(-aR[0]));
      float z0 = fast_rcp(1.f + __expf(-aZ[0]));
      float a0 = aNX[0] + r0 * aNH[0];
      float n0 = 1.f - 2.f * fast_rcp(__expf(2.f * a0) + 1.f);
      ho0 = n0 + z0 * (ho0 - n0);

      float r1 = fast_rcp(1.f + __expf(-aR[1]));
      float z1 = fast_rcp(1.f + __expf(-aZ[1]));
      float a1 = aNX[1] + r1 * aNH[1];
      float n1 = 1.f - 2.f * fast_rcp(__expf(2.f * a1) + 1.f);
      ho1 = n1 + z1 * (ho1 - n1);

      float r2 = fast_rcp(1.f + __expf(-aR[2]));
      float z2 = fast_rcp(1.f + __expf(-aZ[2]));
      float a2 = aNX[2] + r2 * aNH[2];
      float n2 = 1.f - 2.f * fast_rcp(__expf(2.f * a2) + 1.f);
      ho2 = n2 + z2 * (ho2 - n2);

      float r3 = fast_rcp(1.f + __expf(-aR[3]));
      float z3 = fast_rcp(1.f + __expf(-aZ[3]));
      float a3 = aNX[3] + r3 * aNH[3];
      float n3 = 1.f - 2.f * fast_rcp(__expf(2.f * a3) + 1.f);
      ho3 = n3 + z3 * (ho3 - n3);
    }
    // next step writes buffer p^1: no second barrier
  }

  // publish final h (f32)
  if (col == 0) {
    const int hu = wv * 16 + grp * 4;
    h_fin[hu + 0] = ho0;
    h_fin[hu + 1] = ho1;
    h_fin[hu + 2] = ho2;
    h_fin[hu + 3] = ho3;
  }
  __syncthreads();

  // BN (eval) + FC, reduced by wave 0
  if (tid < 64) {
    float pacc = 0.f;
    #pragma unroll
    for (int q = 0; q < 2; ++q) {
      const int k = tid + q * 64;
      const float hv2 = h_fin[k];
      const float nrm = (hv2 - bn_mean[k]) * rsqrtf(bn_var[k] + 1e-5f) * bn_gamma[k] + bn_beta[k];
      pacc += nrm * fc_w[k];
    }
    #pragma unroll
    for (int off = 32; off > 0; off >>= 1) pacc += __shfl_down(pacc, off);
    if (tid == 0) out[b] = pacc + fc_b[0];
  }
}

extern "C" void kernel_launch(void* const* d_in, const int* in_sizes, int n_in,
                              void* d_out, int out_size, void* d_ws, size_t ws_size,
                              hipStream_t stream) {
  const float* x        = (const float*)d_in[0];
  const int*   mask     = (const int*)  d_in[1];
  // d_in[2] = delta (unused by reference forward)
  const float* x_mean   = (const float*)d_in[3];
  const float* w_ih     = (const float*)d_in[4];
  const float* w_hh     = (const float*)d_in[5];
  const float* b_ih     = (const float*)d_in[6];
  const float* b_hh     = (const float*)d_in[7];
  const float* bn_gamma = (const float*)d_in[8];
  const float* bn_beta  = (const float*)d_in[9];
  const float* bn_mean  = (const float*)d_in[10];
  const float* bn_var   = (const float*)d_in[11];
  const float* fc_w     = (const float*)d_in[12];
  const float* fc_b     = (const float*)d_in[13];
  float* out = (float*)d_out;

  gru_fused<<<dim3(BB), dim3(512), 0, stream>>>(
      x, mask, x_mean, w_ih, w_hh, b_ih, b_hh,
      bn_gamma, bn_beta, bn_mean, bn_var, fc_w, fc_b, out);
}

// Round 10
// 1043.381 us; speedup vs baseline: 1.5515x; 1.2974x over previous
//
#include <hip/hip_runtime.h>
#include <cstddef>

#define SS 2048
#define BB 256
#define II 64
#define HH 128

typedef _Float16 h8 __attribute__((ext_vector_type(8)));
typedef _Float16 h2 __attribute__((ext_vector_type(2)));
typedef float    f4 __attribute__((ext_vector_type(4)));
typedef __fp16   fp16v2 __attribute__((ext_vector_type(2)));

__device__ __forceinline__ h2 pack_f16(float a, float b) {
  union { fp16v2 raw; h2 out; } cv;
  cv.raw = __builtin_amdgcn_cvt_pkrtz(a, b);  // RTZ, matches R8's h/xi quantization
  return cv.out;
}
__device__ __forceinline__ float fast_rcp(float v) {
  return __builtin_amdgcn_rcpf(v);
}

// pin to AGPR (weights) / VGPR, blocking rematerialization
#define KEEPA(x) asm volatile("" : "+a"(x))
#define KEEPV(x) asm volatile("" : "+v"(x))

// MFMA, A-operand read DIRECTLY from AGPR (no accvgpr_read copies).
// Chain start: D(v) = A(a)*B(v) + biasC(v); biasC stays live (input only).
__device__ __forceinline__ f4 mfma_first(const h8& a, const h8& b, const f4& c) {
  f4 d;
  asm volatile("v_mfma_f32_16x16x32_f16 %0, %1, %2, %3"
               : "=&v"(d) : "a"(a), "v"(b), "v"(c));
  return d;
}
// Accumulate in place: D==C (MAI accumulation forwarding)
__device__ __forceinline__ void mfma_acc(f4& d, const h8& a, const h8& b) {
  asm volatile("v_mfma_f32_16x16x32_f16 %0, %1, %2, %0"
               : "+v"(d) : "a"(a), "v"(b));
}

// One workgroup per batch element; 512 threads = 8 waves; grid 256 = 1 block/CU.
// Wave wv owns hidden units [16wv,16wv+16). A = W row-tile (AGPR-resident),
// B = h/xi broadcast (16 identical cols) from LDS. C layout (m89): lane l reg q
// -> row (l>>4)*4+q, col l&15. Gate dedup: lane handles q = col&3.
// Accumulation chains are BIT-IDENTICAL to R8 (bias C-init, same chain order,
// RTZ h-store) -- R9's absmax regression came from changing the rounding path.
__global__ __launch_bounds__(512) void gru_fused(
    const float* __restrict__ x,        // [B,S,I]
    const int*   __restrict__ mask,     // [B,S,I]
    const float* __restrict__ x_mean,   // [I]
    const float* __restrict__ w_ih,     // [3H,I]
    const float* __restrict__ w_hh,     // [3H,H]
    const float* __restrict__ b_ih,     // [3H]
    const float* __restrict__ b_hh,     // [3H]
    const float* __restrict__ bn_gamma, // [H]
    const float* __restrict__ bn_beta,  // [H]
    const float* __restrict__ bn_mean,  // [H]
    const float* __restrict__ bn_var,   // [H]
    const float* __restrict__ fc_w,     // [1,H]
    const float* __restrict__ fc_b,     // [1]
    float* __restrict__ out)            // [B,1]
{
  const int b   = blockIdx.x;
  const int tid = threadIdx.x;
  const int wv  = tid >> 6;   // wave 0..7
  const int l   = tid & 63;
  const int col = l & 15;     // A row / C col
  const int grp = l >> 4;     // k-group

  __shared__ __align__(16) _Float16 h_lds[2][HH];
  __shared__ __align__(16) _Float16 xi_lds[2][II];
  __shared__ float h_fin[HH];

  // ---- A-fragments (weights) -> AGPRs, loaded once ----
  // frag elem j = W[row][ kt*32 + grp*8 + j ]
  h8 whA[3][4];  // g in {r,z,n} x 4 k-tiles (K=128)
  h8 wiA[3][2];  // g x 2 k-tiles (K=64)
  #pragma unroll
  for (int g = 0; g < 3; ++g) {
    const int row = g * HH + wv * 16 + col;
    #pragma unroll
    for (int kt = 0; kt < 4; ++kt) {
      const float* pw = w_hh + (size_t)row * HH + kt * 32 + grp * 8;
      float4 va = *reinterpret_cast<const float4*>(pw);
      float4 vb = *reinterpret_cast<const float4*>(pw + 4);
      h8 f;
      f[0]=(_Float16)va.x; f[1]=(_Float16)va.y; f[2]=(_Float16)va.z; f[3]=(_Float16)va.w;
      f[4]=(_Float16)vb.x; f[5]=(_Float16)vb.y; f[6]=(_Float16)vb.z; f[7]=(_Float16)vb.w;
      whA[g][kt] = f;
    }
    #pragma unroll
    for (int kt = 0; kt < 2; ++kt) {
      const float* pw = w_ih + (size_t)row * II + kt * 32 + grp * 8;
      float4 va = *reinterpret_cast<const float4*>(pw);
      float4 vb = *reinterpret_cast<const float4*>(pw + 4);
      h8 f;
      f[0]=(_Float16)va.x; f[1]=(_Float16)va.y; f[2]=(_Float16)va.z; f[3]=(_Float16)va.w;
      f[4]=(_Float16)vb.x; f[5]=(_Float16)vb.y; f[6]=(_Float16)vb.z; f[7]=(_Float16)vb.w;
      wiA[g][kt] = f;
    }
  }
  #pragma unroll
  for (int g = 0; g < 3; ++g) {
    #pragma unroll
    for (int kt = 0; kt < 4; ++kt) KEEPA(whA[g][kt]);
    #pragma unroll
    for (int kt = 0; kt < 2; ++kt) KEEPA(wiA[g][kt]);
  }

  // ---- bias C-init fragments (persistent; chains start from these, as R8) ----
  f4 bRf, bZf, bNXf, bNHf;
  #pragma unroll
  for (int q = 0; q < 4; ++q) {
    const int hu = wv * 16 + grp * 4 + q;
    bRf[q]  = b_ih[hu]        + b_hh[hu];
    bZf[q]  = b_ih[HH + hu]   + b_hh[HH + hu];
    bNXf[q] = b_ih[2*HH + hu];
    bNHf[q] = b_hh[2*HH + hu];
  }
  KEEPV(bRf); KEEPV(bZf); KEEPV(bNXf); KEEPV(bNHf);

  // per-lane gate slot: q = col&3
  const int q_l  = col & 3;
  const int hu_l = wv * 16 + grp * 4 + q_l;
  const bool cs1 = (col & 1) != 0;
  const bool cs2 = (col & 2) != 0;
  const bool wlead = (col < 4);          // writer lanes

  // ---- prologue: LOCF state (32 writer threads x 2 channels) + prefetch ----
  const size_t xbase = (size_t)b * SS * II;
  float last0 = 0.f, last1 = 0.f;
  float2 xn = {0.f, 0.f};
  int2   mn = {0, 0};
  const float2* xq = reinterpret_cast<const float2*>(x + xbase + II) + tid;
  const int2*   mq = reinterpret_cast<const int2*>(mask + xbase + II) + tid;
  if (tid < 32) {
    float2 xm0 = reinterpret_cast<const float2*>(x_mean)[tid];
    last0 = xm0.x; last1 = xm0.y;
    xn = reinterpret_cast<const float2*>(x + xbase)[tid];
    mn = reinterpret_cast<const int2*>(mask + xbase)[tid];
  }
  float ho = 0.f;  // h[t-1][hu_l], f32, one per lane

  for (int t = 0; t < SS; ++t) {
    const int p = t & 1;
    // publish xi[t] and h[t-1] into buffer p (RTZ, matching R8)
    if (tid < 32) {
      last0 = (mn.x > 0) ? xn.x : last0;
      last1 = (mn.y > 0) ? xn.y : last1;
      reinterpret_cast<h2*>(&xi_lds[p][0])[tid] = pack_f16(last0, last1);
    }
    if (wlead) h_lds[p][hu_l] = pack_f16(ho, ho).x;
    __syncthreads();  // one barrier/step; double-buffer covers WAR

    // prefetch t+1
    if (tid < 32 && t + 1 < SS) {
      xn = *xq;  mn = *mq;
      xq += 32;  mq += 32;
    }

    // B-fragments: 8 contiguous f16 (16-lane broadcast, conflict-free)
    h8 hB[4], xB[2];
    #pragma unroll
    for (int kt = 0; kt < 4; ++kt)
      hB[kt] = *reinterpret_cast<const h8*>(&h_lds[p][kt * 32 + grp * 8]);
    #pragma unroll
    for (int kt = 0; kt < 2; ++kt)
      xB[kt] = *reinterpret_cast<const h8*>(&xi_lds[p][kt * 32 + grp * 8]);

    // 18 MFMAs, chains exactly as R8: {bias -> hh0..3 -> ih0..1}
    f4 aR  = mfma_first(whA[0][0], hB[0], bRf);
    f4 aZ  = mfma_first(whA[1][0], hB[0], bZf);
    f4 aNH = mfma_first(whA[2][0], hB[0], bNHf);
    #pragma unroll
    for (int kt = 1; kt < 4; ++kt) {
      mfma_acc(aR,  whA[0][kt], hB[kt]);
      mfma_acc(aZ,  whA[1][kt], hB[kt]);
      mfma_acc(aNH, whA[2][kt], hB[kt]);
    }
    f4 aNX = mfma_first(wiA[2][0], xB[0], bNXf);
    mfma_acc(aR,  wiA[0][0], xB[0]);
    mfma_acc(aZ,  wiA[1][0], xB[0]);
    mfma_acc(aNX, wiA[2][1], xB[1]);
    mfma_acc(aR,  wiA[0][1], xB[1]);
    mfma_acc(aZ,  wiA[1][1], xB[1]);
    // MFMA DstD -> VALU read hazard fence; sched_barrier keeps the selects
    // (non-volatile VALU) from being hoisted into the hazard window (rule #18)
    asm volatile("s_nop 7\n\ts_nop 7");
    __builtin_amdgcn_sched_barrier(0);

    // dedup: lane picks its q = col&3 (3 cndmask each, masks loop-invariant)
    const float sR  = cs2 ? (cs1 ? aR[3]  : aR[2])  : (cs1 ? aR[1]  : aR[0]);
    const float sZ  = cs2 ? (cs1 ? aZ[3]  : aZ[2])  : (cs1 ? aZ[1]  : aZ[0]);
    const float sNX = cs2 ? (cs1 ? aNX[3] : aNX[2]) : (cs1 ? aNX[1] : aNX[0]);
    const float sNH = cs2 ? (cs1 ? aNH[3] : aNH[2]) : (cs1 ? aNH[1] : aNH[0]);

    // one gate set per lane (same formulas as R8)
    {
      float r = fast_rcp(1.f + __expf(-sR));
      float z = fast_rcp(1.f + __expf(-sZ));
      float a = sNX + r * sNH;
      float n = 1.f - 2.f * fast_rcp(__expf(2.f * a) + 1.f);
      ho = n + z * (ho - n);
    }
    // next step writes buffer p^1: no second barrier
  }

  // publish final h (f32)
  if (wlead) h_fin[hu_l] = ho;
  __syncthreads();

  // BN (eval) + FC, reduced by wave 0
  if (tid < 64) {
    float pacc = 0.f;
    #pragma unroll
    for (int q = 0; q < 2; ++q) {
      const int k = tid + q * 64;
      const float hv2 = h_fin[k];
      const float nrm = (hv2 - bn_mean[k]) * rsqrtf(bn_var[k] + 1e-5f) * bn_gamma[k] + bn_beta[k];
      pacc += nrm * fc_w[k];
    }
    #pragma unroll
    for (int off = 32; off > 0; off >>= 1) pacc += __shfl_down(pacc, off);
    if (tid == 0) out[b] = pacc + fc_b[0];
  }
}

extern "C" void kernel_launch(void* const* d_in, const int* in_sizes, int n_in,
                              void* d_out, int out_size, void* d_ws, size_t ws_size,
                              hipStream_t stream) {
  const float* x        = (const float*)d_in[0];
  const int*   mask     = (const int*)  d_in[1];
  // d_in[2] = delta (unused by reference forward)
  const float* x_mean   = (const float*)d_in[3];
  const float* w_ih     = (const float*)d_in[4];
  const float* w_hh     = (const float*)d_in[5];
  const float* b_ih     = (const float*)d_in[6];
  const float* b_hh     = (const float*)d_in[7];
  const float* bn_gamma = (const float*)d_in[8];
  const float* bn_beta  = (const float*)d_in[9];
  const float* bn_mean  = (const float*)d_in[10];
  const float* bn_var   = (const float*)d_in[11];
  const float* fc_w     = (const float*)d_in[12];
  const float* fc_b     = (const float*)d_in[13];
  float* out = (float*)d_out;

  gru_fused<<<dim3(BB), dim3(512), 0, stream>>>(
      x, mask, x_mean, w_ih, w_hh, b_ih, b_hh,
      bn_gamma, bn_beta, bn_mean, bn_var, fc_w, fc_b, out);
}

// Round 11
// 1031.438 us; speedup vs baseline: 1.5695x; 1.0116x over previous
//
#include <hip/hip_runtime.h>
#include <cstddef>

#define SS 2048
#define BB 256
#define II 64
#define HH 128

typedef _Float16 h8 __attribute__((ext_vector_type(8)));
typedef _Float16 h2 __attribute__((ext_vector_type(2)));
typedef float    f4 __attribute__((ext_vector_type(4)));
typedef __fp16   fp16v2 __attribute__((ext_vector_type(2)));

__device__ __forceinline__ h2 pack_f16(float a, float b) {
  union { fp16v2 raw; h2 out; } cv;
  cv.raw = __builtin_amdgcn_cvt_pkrtz(a, b);  // RTZ, matches R8/R10 quantization
  return cv.out;
}
__device__ __forceinline__ float fast_rcp(float v) {
  return __builtin_amdgcn_rcpf(v);
}

// pin to AGPR (weights) / VGPR, blocking rematerialization
#define KEEPA(x) asm volatile("" : "+a"(x))
#define KEEPV(x) asm volatile("" : "+v"(x))

// MFMA, A-operand read DIRECTLY from AGPR (no accvgpr_read copies).
__device__ __forceinline__ f4 mfma_first(const h8& a, const h8& b, const f4& c) {
  f4 d;
  asm volatile("v_mfma_f32_16x16x32_f16 %0, %1, %2, %3"
               : "=&v"(d) : "a"(a), "v"(b), "v"(c));
  return d;
}
__device__ __forceinline__ void mfma_acc(f4& d, const h8& a, const h8& b) {
  asm volatile("v_mfma_f32_16x16x32_f16 %0, %1, %2, %0"
               : "+v"(d) : "a"(a), "v"(b));
}

// LDS-only barrier: drain lgkm (our ds ops) but leave global prefetch loads
// in flight. __syncthreads would emit s_waitcnt vmcnt(0) before s_barrier,
// serializing an HBM-latency load into EVERY step (the m97 barrier drain).
// Cross-wave data flows ONLY through LDS here, so lgkm-drain is sufficient.
__device__ __forceinline__ void lds_barrier() {
  asm volatile("s_waitcnt lgkmcnt(0)" ::: "memory");
  __builtin_amdgcn_s_barrier();
}

// One workgroup per batch element; 512 threads = 8 waves; grid 256 = 1 block/CU.
// Wave wv owns hidden units [16wv,16wv+16). A = W row-tile (AGPR-resident),
// B = h/xi broadcast (16 identical cols) from LDS. C layout (m89): lane l reg q
// -> row (l>>4)*4+q, col l&15. Gate dedup: lane handles q = col&3.
// Numerics bit-identical to R8/R10 (bias C-init, same chain order, RTZ stores).
__global__ __launch_bounds__(512) void gru_fused(
    const float* __restrict__ x,        // [B,S,I]
    const int*   __restrict__ mask,     // [B,S,I]
    const float* __restrict__ x_mean,   // [I]
    const float* __restrict__ w_ih,     // [3H,I]
    const float* __restrict__ w_hh,     // [3H,H]
    const float* __restrict__ b_ih,     // [3H]
    const float* __restrict__ b_hh,     // [3H]
    const float* __restrict__ bn_gamma, // [H]
    const float* __restrict__ bn_beta,  // [H]
    const float* __restrict__ bn_mean,  // [H]
    const float* __restrict__ bn_var,   // [H]
    const float* __restrict__ fc_w,     // [1,H]
    const float* __restrict__ fc_b,     // [1]
    float* __restrict__ out)            // [B,1]
{
  const int b   = blockIdx.x;
  const int tid = threadIdx.x;
  const int wv  = tid >> 6;   // wave 0..7
  const int l   = tid & 63;
  const int col = l & 15;     // A row / C col
  const int grp = l >> 4;     // k-group

  __shared__ __align__(16) _Float16 h_lds[2][HH];
  __shared__ __align__(16) _Float16 xi_lds[2][II];
  __shared__ float h_fin[HH];

  // ---- A-fragments (weights) -> AGPRs, loaded once ----
  h8 whA[3][4];  // g in {r,z,n} x 4 k-tiles (K=128)
  h8 wiA[3][2];  // g x 2 k-tiles (K=64)
  #pragma unroll
  for (int g = 0; g < 3; ++g) {
    const int row = g * HH + wv * 16 + col;
    #pragma unroll
    for (int kt = 0; kt < 4; ++kt) {
      const float* pw = w_hh + (size_t)row * HH + kt * 32 + grp * 8;
      float4 va = *reinterpret_cast<const float4*>(pw);
      float4 vb = *reinterpret_cast<const float4*>(pw + 4);
      h8 f;
      f[0]=(_Float16)va.x; f[1]=(_Float16)va.y; f[2]=(_Float16)va.z; f[3]=(_Float16)va.w;
      f[4]=(_Float16)vb.x; f[5]=(_Float16)vb.y; f[6]=(_Float16)vb.z; f[7]=(_Float16)vb.w;
      whA[g][kt] = f;
    }
    #pragma unroll
    for (int kt = 0; kt < 2; ++kt) {
      const float* pw = w_ih + (size_t)row * II + kt * 32 + grp * 8;
      float4 va = *reinterpret_cast<const float4*>(pw);
      float4 vb = *reinterpret_cast<const float4*>(pw + 4);
      h8 f;
      f[0]=(_Float16)va.x; f[1]=(_Float16)va.y; f[2]=(_Float16)va.z; f[3]=(_Float16)va.w;
      f[4]=(_Float16)vb.x; f[5]=(_Float16)vb.y; f[6]=(_Float16)vb.z; f[7]=(_Float16)vb.w;
      wiA[g][kt] = f;
    }
  }
  #pragma unroll
  for (int g = 0; g < 3; ++g) {
    #pragma unroll
    for (int kt = 0; kt < 4; ++kt) KEEPA(whA[g][kt]);
    #pragma unroll
    for (int kt = 0; kt < 2; ++kt) KEEPA(wiA[g][kt]);
  }

  // ---- bias C-init fragments (persistent; chains start from these) ----
  f4 bRf, bZf, bNXf, bNHf;
  #pragma unroll
  for (int q = 0; q < 4; ++q) {
    const int hu = wv * 16 + grp * 4 + q;
    bRf[q]  = b_ih[hu]        + b_hh[hu];
    bZf[q]  = b_ih[HH + hu]   + b_hh[HH + hu];
    bNXf[q] = b_ih[2*HH + hu];
    bNHf[q] = b_hh[2*HH + hu];
  }
  KEEPV(bRf); KEEPV(bZf); KEEPV(bNXf); KEEPV(bNHf);

  // per-lane gate slot: q = col&3
  const int q_l  = col & 3;
  const int hu_l = wv * 16 + grp * 4 + q_l;
  const bool cs1 = (col & 1) != 0;
  const bool cs2 = (col & 2) != 0;
  const bool wlead = (col < 4);          // writer lanes

  // ---- prologue: LOCF state + 2-deep prefetch (regs per parity: no runtime
  // selects between in-flight registers -> no premature vmcnt waits) ----
  const size_t xbase = (size_t)b * SS * II;
  float last0 = 0.f, last1 = 0.f;
  float2 xnA = {0.f, 0.f}, xnB = {0.f, 0.f};
  int2   mnA = {0, 0},     mnB = {0, 0};
  const float2* xq = reinterpret_cast<const float2*>(x + xbase + 2 * II) + tid;
  const int2*   mq = reinterpret_cast<const int2*>(mask + xbase + 2 * II) + tid;
  if (tid < 32) {
    float2 xm0 = reinterpret_cast<const float2*>(x_mean)[tid];
    last0 = xm0.x; last1 = xm0.y;
    xnA = reinterpret_cast<const float2*>(x + xbase)[tid];          // x[0]
    mnA = reinterpret_cast<const int2*>(mask + xbase)[tid];
    xnB = reinterpret_cast<const float2*>(x + xbase + II)[tid];     // x[1]
    mnB = reinterpret_cast<const int2*>(mask + xbase + II)[tid];
  }
  float ho = 0.f;  // h[t-1][hu_l], f32, one per lane

  // body for one timestep; XN/MN are the parity's registers (static).
#define GRU_STEP(T, XN, MN)                                                    \
  {                                                                            \
    const int p = (T) & 1;                                                     \
    if (tid < 32) {                                                            \
      last0 = (MN.x > 0) ? XN.x : last0;                                       \
      last1 = (MN.y > 0) ? XN.y : last1;                                       \
      reinterpret_cast<h2*>(&xi_lds[p][0])[tid] = pack_f16(last0, last1);      \
    }                                                                          \
    if (wlead) h_lds[p][hu_l] = pack_f16(ho, ho).x;                            \
    lds_barrier();                                                             \
    if (tid < 32 && (T) + 2 < SS) {                                            \
      XN = *xq;  MN = *mq;                                                     \
      xq += 32;  mq += 32;                                                     \
    }                                                                          \
    h8 hB[4], xB[2];                                                           \
    _Pragma("unroll")                                                          \
    for (int kt = 0; kt < 4; ++kt)                                             \
      hB[kt] = *reinterpret_cast<const h8*>(&h_lds[p][kt * 32 + grp * 8]);     \
    _Pragma("unroll")                                                          \
    for (int kt = 0; kt < 2; ++kt)                                             \
      xB[kt] = *reinterpret_cast<const h8*>(&xi_lds[p][kt * 32 + grp * 8]);    \
    f4 aR  = mfma_first(whA[0][0], hB[0], bRf);                                \
    f4 aZ  = mfma_first(whA[1][0], hB[0], bZf);                                \
    f4 aNH = mfma_first(whA[2][0], hB[0], bNHf);                               \
    _Pragma("unroll")                                                          \
    for (int kt = 1; kt < 4; ++kt) {                                           \
      mfma_acc(aR,  whA[0][kt], hB[kt]);                                       \
      mfma_acc(aZ,  whA[1][kt], hB[kt]);                                       \
      mfma_acc(aNH, whA[2][kt], hB[kt]);                                       \
    }                                                                          \
    f4 aNX = mfma_first(wiA[2][0], xB[0], bNXf);                               \
    mfma_acc(aR,  wiA[0][0], xB[0]);                                           \
    mfma_acc(aZ,  wiA[1][0], xB[0]);                                           \
    mfma_acc(aNX, wiA[2][1], xB[1]);                                           \
    mfma_acc(aR,  wiA[0][1], xB[1]);                                           \
    mfma_acc(aZ,  wiA[1][1], xB[1]);                                           \
    asm volatile("s_nop 7\n\ts_nop 7");                                        \
    __builtin_amdgcn_sched_barrier(0);                                         \
    const float sR  = cs2 ? (cs1 ? aR[3]  : aR[2])  : (cs1 ? aR[1]  : aR[0]);  \
    const float sZ  = cs2 ? (cs1 ? aZ[3]  : aZ[2])  : (cs1 ? aZ[1]  : aZ[0]);  \
    const float sNX = cs2 ? (cs1 ? aNX[3] : aNX[2]) : (cs1 ? aNX[1] : aNX[0]); \
    const float sNH = cs2 ? (cs1 ? aNH[3] : aNH[2]) : (cs1 ? aNH[1] : aNH[0]); \
    {                                                                          \
      float r = fast_rcp(1.f + __expf(-sR));                                   \
      float z = fast_rcp(1.f + __expf(-sZ));                                   \
      float a = sNX + r * sNH;                                                 \
      float n = 1.f - 2.f * fast_rcp(__expf(2.f * a) + 1.f);                   \
      ho = n + z * (ho - n);                                                   \
    }                                                                          \
  }

  for (int t = 0; t < SS; t += 2) {
    GRU_STEP(t,     xnA, mnA)
    GRU_STEP(t + 1, xnB, mnB)
  }
#undef GRU_STEP

  // publish final h (f32)
  if (wlead) h_fin[hu_l] = ho;
  __syncthreads();

  // BN (eval) + FC, reduced by wave 0
  if (tid < 64) {
    float pacc = 0.f;
    #pragma unroll
    for (int q = 0; q < 2; ++q) {
      const int k = tid + q * 64;
      const float hv2 = h_fin[k];
      const float nrm = (hv2 - bn_mean[k]) * rsqrtf(bn_var[k] + 1e-5f) * bn_gamma[k] + bn_beta[k];
      pacc += nrm * fc_w[k];
    }
    #pragma unroll
    for (int off = 32; off > 0; off >>= 1) pacc += __shfl_down(pacc, off);
    if (tid == 0) out[b] = pacc + fc_b[0];
  }
}

extern "C" void kernel_launch(void* const* d_in, const int* in_sizes, int n_in,
                              void* d_out, int out_size, void* d_ws, size_t ws_size,
                              hipStream_t stream) {
  const float* x        = (const float*)d_in[0];
  const int*   mask     = (const int*)  d_in[1];
  // d_in[2] = delta (unused by reference forward)
  const float* x_mean   = (const float*)d_in[3];
  const float* w_ih     = (const float*)d_in[4];
  const float* w_hh     = (const float*)d_in[5];
  const float* b_ih     = (const float*)d_in[6];
  const float* b_hh     = (const float*)d_in[7];
  const float* bn_gamma = (const float*)d_in[8];
  const float* bn_beta  = (const float*)d_in[9];
  const float* bn_mean  = (const float*)d_in[10];
  const float* bn_var   = (const float*)d_in[11];
  const float* fc_w     = (const float*)d_in[12];
  const float* fc_b     = (const float*)d_in[13];
  float* out = (float*)d_out;

  gru_fused<<<dim3(BB), dim3(512), 0, stream>>>(
      x, mask, x_mean, w_ih, w_hh, b_ih, b_hh,
      bn_gamma, bn_beta, bn_mean, bn_var, fc_w, fc_b, out);
}

// Round 12
// 823.828 us; speedup vs baseline: 1.9650x; 1.2520x over previous
//
#include <hip/hip_runtime.h>
#include <cstddef>

#define SS 2048
#define BB 256
#define II 64
#define HH 128

typedef _Float16 h8 __attribute__((ext_vector_type(8)));
typedef _Float16 h2 __attribute__((ext_vector_type(2)));
typedef float    f4 __attribute__((ext_vector_type(4)));
typedef __fp16   fp16v2 __attribute__((ext_vector_type(2)));

__device__ __forceinline__ h2 pack_f16(float a, float b) {
  union { fp16v2 raw; h2 out; } cv;
  cv.raw = __builtin_amdgcn_cvt_pkrtz(a, b);  // RTZ, matches R8/R10/R11
  return cv.out;
}
__device__ __forceinline__ float fast_rcp(float v) {
  return __builtin_amdgcn_rcpf(v);
}

#define KEEPA(x) asm volatile("" : "+a"(x))
#define KEEPV(x) asm volatile("" : "+v"(x))

// MFMA, A-operand read DIRECTLY from AGPR
__device__ __forceinline__ f4 mfma_first(const h8& a, const h8& b, const f4& c) {
  f4 d;
  asm volatile("v_mfma_f32_16x16x32_f16 %0, %1, %2, %3"
               : "=&v"(d) : "a"(a), "v"(b), "v"(c));
  return d;
}
__device__ __forceinline__ void mfma_acc(f4& d, const h8& a, const h8& b) {
  asm volatile("v_mfma_f32_16x16x32_f16 %0, %1, %2, %0"
               : "+v"(d) : "a"(a), "v"(b));
}

// LDS-only barrier (global prefetch loads stay in flight)
__device__ __forceinline__ void lds_barrier() {
  asm volatile("s_waitcnt lgkmcnt(0)" ::: "memory");
  __builtin_amdgcn_s_barrier();
}

// One workgroup per batch element; 512 threads = 8 waves; grid 256 = 1 block/CU.
// hh: per step, 12 MFMA/wave (bias C-init chain, bit-identical to R10).
// ih: amortized -- every 16 steps one batched GEMM with B cols = 16 TIMESTEPS
//     (xi is non-recurrent), results parked in gx_lds[3][16][128] f32.
// C layout (m89): lane l reg q -> row (l>>4)*4+q, col l&15. B col = l&15.
__global__ __launch_bounds__(512) void gru_fused(
    const float* __restrict__ x,        // [B,S,I]
    const int*   __restrict__ mask,     // [B,S,I]
    const float* __restrict__ x_mean,   // [I]
    const float* __restrict__ w_ih,     // [3H,I]
    const float* __restrict__ w_hh,     // [3H,H]
    const float* __restrict__ b_ih,     // [3H]
    const float* __restrict__ b_hh,     // [3H]
    const float* __restrict__ bn_gamma, // [H]
    const float* __restrict__ bn_beta,  // [H]
    const float* __restrict__ bn_mean,  // [H]
    const float* __restrict__ bn_var,   // [H]
    const float* __restrict__ fc_w,     // [1,H]
    const float* __restrict__ fc_b,     // [1]
    float* __restrict__ out)            // [B,1]
{
  const int b   = blockIdx.x;
  const int tid = threadIdx.x;
  const int wv  = tid >> 6;   // wave 0..7
  const int l   = tid & 63;
  const int col = l & 15;     // A row / C-col (= timestep in ih-GEMM)
  const int grp = l >> 4;     // k-group

  __shared__ __align__(16) _Float16 h_lds[2][HH];
  __shared__ __align__(16) _Float16 xi_st[16][72];   // 16 steps staged, +8 pad
  __shared__ __align__(16) float gx_lds[3][16][HH];  // [gate][tau][hu]
  __shared__ float h_fin[HH];

  // ---- A-fragments (weights) -> AGPRs, loaded once ----
  h8 whA[3][4];  // g in {r,z,n} x 4 k-tiles (K=128)
  h8 wiA[3][2];  // g x 2 k-tiles (K=64)
  #pragma unroll
  for (int g = 0; g < 3; ++g) {
    const int row = g * HH + wv * 16 + col;
    #pragma unroll
    for (int kt = 0; kt < 4; ++kt) {
      const float* pw = w_hh + (size_t)row * HH + kt * 32 + grp * 8;
      float4 va = *reinterpret_cast<const float4*>(pw);
      float4 vb = *reinterpret_cast<const float4*>(pw + 4);
      h8 f;
      f[0]=(_Float16)va.x; f[1]=(_Float16)va.y; f[2]=(_Float16)va.z; f[3]=(_Float16)va.w;
      f[4]=(_Float16)vb.x; f[5]=(_Float16)vb.y; f[6]=(_Float16)vb.z; f[7]=(_Float16)vb.w;
      whA[g][kt] = f;
    }
    #pragma unroll
    for (int kt = 0; kt < 2; ++kt) {
      const float* pw = w_ih + (size_t)row * II + kt * 32 + grp * 8;
      float4 va = *reinterpret_cast<const float4*>(pw);
      float4 vb = *reinterpret_cast<const float4*>(pw + 4);
      h8 f;
      f[0]=(_Float16)va.x; f[1]=(_Float16)va.y; f[2]=(_Float16)va.z; f[3]=(_Float16)va.w;
      f[4]=(_Float16)vb.x; f[5]=(_Float16)vb.y; f[6]=(_Float16)vb.z; f[7]=(_Float16)vb.w;
      wiA[g][kt] = f;
    }
  }
  #pragma unroll
  for (int g = 0; g < 3; ++g) {
    #pragma unroll
    for (int kt = 0; kt < 4; ++kt) KEEPA(whA[g][kt]);
    #pragma unroll
    for (int kt = 0; kt < 2; ++kt) KEEPA(wiA[g][kt]);
  }

  // bias C-init fragments (hh chains start from bR/bZ/bNH; ih-NX chain from bNX)
  f4 bRf, bZf, bNXf, bNHf;
  #pragma unroll
  for (int q = 0; q < 4; ++q) {
    const int hu = wv * 16 + grp * 4 + q;
    bRf[q]  = b_ih[hu]        + b_hh[hu];
    bZf[q]  = b_ih[HH + hu]   + b_hh[HH + hu];
    bNXf[q] = b_ih[2*HH + hu];
    bNHf[q] = b_hh[2*HH + hu];
  }
  f4 zf = {0.f, 0.f, 0.f, 0.f};
  KEEPV(bRf); KEEPV(bZf); KEEPV(bNXf); KEEPV(bNHf); KEEPV(zf);

  // per-lane gate slot
  const int q_l  = col & 3;
  const int hu_l = wv * 16 + grp * 4 + q_l;
  const bool cs1 = (col & 1) != 0;
  const bool cs2 = (col & 2) != 0;
  const bool wlead = (col < 4);

  // ---- LOCF staging: 64 writer threads, one channel each, 16 steps/group ----
  const size_t xbase = (size_t)b * SS * II;
  const float* xg = x + xbase;
  const int*   mg = mask + xbase;
  float last = 0.f;
  float x_stg[16];
  int   m_stg[16];
  if (tid < 64) {
    last = x_mean[tid];
    #pragma unroll
    for (int u = 0; u < 16; ++u) {
      x_stg[u] = xg[u * II + tid];
      m_stg[u] = mg[u * II + tid];
    }
  }
  float ho = 0.f;  // h[t-1][hu_l], f32

  for (int gq = 0; gq < SS / 16; ++gq) {
    // ---- group boundary: LOCF -> xi_st, prefetch next group ----
    if (tid < 64) {
      #pragma unroll
      for (int u = 0; u < 16; ++u) {
        last = (m_stg[u] > 0) ? x_stg[u] : last;
        xi_st[u][tid] = pack_f16(last, last).x;
      }
      if (gq + 1 < SS / 16) {
        const float* xn = xg + (gq + 1) * 16 * II;
        const int*   mn = mg + (gq + 1) * 16 * II;
        #pragma unroll
        for (int u = 0; u < 16; ++u) {
          x_stg[u] = xn[u * II + tid];
          m_stg[u] = mn[u * II + tid];
        }
      }
    }
    lds_barrier();  // xi_st visible

    // ---- ih-GEMM: 6 MFMAs, B cols = 16 timesteps ----
    h8 xB0 = *reinterpret_cast<const h8*>(&xi_st[col][grp * 8]);
    h8 xB1 = *reinterpret_cast<const h8*>(&xi_st[col][32 + grp * 8]);
    f4 gR  = mfma_first(wiA[0][0], xB0, zf);
    f4 gZ  = mfma_first(wiA[1][0], xB0, zf);
    f4 gNX = mfma_first(wiA[2][0], xB0, bNXf);
    mfma_acc(gR,  wiA[0][1], xB1);
    mfma_acc(gZ,  wiA[1][1], xB1);
    mfma_acc(gNX, wiA[2][1], xB1);
    asm volatile("s_nop 7\n\ts_nop 7");
    __builtin_amdgcn_sched_barrier(0);
    *reinterpret_cast<f4*>(&gx_lds[0][col][wv * 16 + grp * 4]) = gR;
    *reinterpret_cast<f4*>(&gx_lds[1][col][wv * 16 + grp * 4]) = gZ;
    *reinterpret_cast<f4*>(&gx_lds[2][col][wv * 16 + grp * 4]) = gNX;
    // visibility of gx/h covered by the tau=0 lds_barrier below

    // ---- 16 recurrence steps (fully unrolled: all LDS offsets immediate) ----
    #pragma unroll
    for (int tau = 0; tau < 16; ++tau) {
      const int p = tau & 1;
      if (wlead) h_lds[p][hu_l] = pack_f16(ho, ho).x;
      lds_barrier();

      h8 hB[4];
      #pragma unroll
      for (int kt = 0; kt < 4; ++kt)
        hB[kt] = *reinterpret_cast<const h8*>(&h_lds[p][kt * 32 + grp * 8]);

      // 12 hh MFMAs, chains bit-identical to R10: {bias -> hh0..3}
      f4 aR  = mfma_first(whA[0][0], hB[0], bRf);
      f4 aZ  = mfma_first(whA[1][0], hB[0], bZf);
      f4 aNH = mfma_first(whA[2][0], hB[0], bNHf);
      #pragma unroll
      for (int kt = 1; kt < 4; ++kt) {
        mfma_acc(aR,  whA[0][kt], hB[kt]);
        mfma_acc(aZ,  whA[1][kt], hB[kt]);
        mfma_acc(aNH, whA[2][kt], hB[kt]);
      }
      asm volatile("s_nop 7\n\ts_nop 7");
      __builtin_amdgcn_sched_barrier(0);

      // gx reads: hu-indexed, conflict-free (16 banks x 4-lane broadcast)
      const float gxR = gx_lds[0][tau][hu_l];
      const float gxZ = gx_lds[1][tau][hu_l];
      const float sNX = gx_lds[2][tau][hu_l];

      const float sR  = (cs2 ? (cs1 ? aR[3]  : aR[2])  : (cs1 ? aR[1]  : aR[0]))  + gxR;
      const float sZ  = (cs2 ? (cs1 ? aZ[3]  : aZ[2])  : (cs1 ? aZ[1]  : aZ[0]))  + gxZ;
      const float sNH =  cs2 ? (cs1 ? aNH[3] : aNH[2]) : (cs1 ? aNH[1] : aNH[0]);

      float r = fast_rcp(1.f + __expf(-sR));
      float z = fast_rcp(1.f + __expf(-sZ));
      float a = sNX + r * sNH;
      float n = 1.f - 2.f * fast_rcp(__expf(2.f * a) + 1.f);
      ho = n + z * (ho - n);
    }
  }

  // publish final h (f32)
  if (wlead) h_fin[hu_l] = ho;
  __syncthreads();

  // BN (eval) + FC, reduced by wave 0
  if (tid < 64) {
    float pacc = 0.f;
    #pragma unroll
    for (int q = 0; q < 2; ++q) {
      const int k = tid + q * 64;
      const float hv2 = h_fin[k];
      const float nrm = (hv2 - bn_mean[k]) * rsqrtf(bn_var[k] + 1e-5f) * bn_gamma[k] + bn_beta[k];
      pacc += nrm * fc_w[k];
    }
    #pragma unroll
    for (int off = 32; off > 0; off >>= 1) pacc += __shfl_down(pacc, off);
    if (tid == 0) out[b] = pacc + fc_b[0];
  }
}

extern "C" void kernel_launch(void* const* d_in, const int* in_sizes, int n_in,
                              void* d_out, int out_size, void* d_ws, size_t ws_size,
                              hipStream_t stream) {
  const float* x        = (const float*)d_in[0];
  const int*   mask     = (const int*)  d_in[1];
  // d_in[2] = delta (unused by reference forward)
  const float* x_mean   = (const float*)d_in[3];
  const float* w_ih     = (const float*)d_in[4];
  const float* w_hh     = (const float*)d_in[5];
  const float* b_ih     = (const float*)d_in[6];
  const float* b_hh     = (const float*)d_in[7];
  const float* bn_gamma = (const float*)d_in[8];
  const float* bn_beta  = (const float*)d_in[9];
  const float* bn_mean  = (const float*)d_in[10];
  const float* bn_var   = (const float*)d_in[11];
  const float* fc_w     = (const float*)d_in[12];
  const float* fc_b     = (const float*)d_in[13];
  float* out = (float*)d_out;

  gru_fused<<<dim3(BB), dim3(512), 0, stream>>>(
      x, mask, x_mean, w_ih, w_hh, b_ih, b_hh,
      bn_gamma, bn_beta, bn_mean, bn_var, fc_w, fc_b, out);
}

// Round 13
// 756.090 us; speedup vs baseline: 2.1410x; 1.0896x over previous
//
#include <hip/hip_runtime.h>
#include <cstddef>

#define SS 2048
#define BB 256
#define II 64
#define HH 128
#define GROUP 16
#define NG (SS / GROUP)

typedef _Float16 h8 __attribute__((ext_vector_type(8)));
typedef _Float16 h2 __attribute__((ext_vector_type(2)));
typedef float    f4 __attribute__((ext_vector_type(4)));
typedef __fp16   fp16v2 __attribute__((ext_vector_type(2)));

__device__ __forceinline__ h2 pack_f16(float a, float b) {
  union { fp16v2 raw; h2 out; } cv;
  cv.raw = __builtin_amdgcn_cvt_pkrtz(a, b);  // RTZ, matches R8..R12
  return cv.out;
}
__device__ __forceinline__ float fast_rcp(float v) {
  return __builtin_amdgcn_rcpf(v);
}

#define KEEPA(x) asm volatile("" : "+a"(x))
#define KEEPV(x) asm volatile("" : "+v"(x))

// MFMA, A-operand read DIRECTLY from AGPR
__device__ __forceinline__ f4 mfma_first(const h8& a, const h8& b, const f4& c) {
  f4 d;
  asm volatile("v_mfma_f32_16x16x32_f16 %0, %1, %2, %3"
               : "=&v"(d) : "a"(a), "v"(b), "v"(c));
  return d;
}
__device__ __forceinline__ void mfma_acc(f4& d, const h8& a, const h8& b) {
  asm volatile("v_mfma_f32_16x16x32_f16 %0, %1, %2, %0"
               : "+v"(d) : "a"(a), "v"(b));
}

// LDS-only barrier (global prefetch loads stay in flight)
__device__ __forceinline__ void lds_barrier() {
  asm volatile("s_waitcnt lgkmcnt(0)" ::: "memory");
  __builtin_amdgcn_s_barrier();
}

// One workgroup per batch element; 512 threads = 8 waves; grid 256 = 1 block/CU.
// hh: 12 MFMA/wave/step (bias C-init chains, bit-identical to R10/R12).
// ih: merged into tau=0 of each 16-step group (6 extra MFMAs fill the pipe);
//     gx is INTRA-WAVE (writer lane col==tau, reader same wave) -> no barrier,
//     just lgkmcnt(0). gx layout [gate][hu][17] : b32 writes <=2-way banked,
//     reads 17*hu mod 32 injective -> conflict-free (R12's [tau][128] f4
//     writes were 16-way conflicted, 4.6e7 cycles).
__global__ __launch_bounds__(512) void gru_fused(
    const float* __restrict__ x,        // [B,S,I]
    const int*   __restrict__ mask,     // [B,S,I]
    const float* __restrict__ x_mean,   // [I]
    const float* __restrict__ w_ih,     // [3H,I]
    const float* __restrict__ w_hh,     // [3H,H]
    const float* __restrict__ b_ih,     // [3H]
    const float* __restrict__ b_hh,     // [3H]
    const float* __restrict__ bn_gamma, // [H]
    const float* __restrict__ bn_beta,  // [H]
    const float* __restrict__ bn_mean,  // [H]
    const float* __restrict__ bn_var,   // [H]
    const float* __restrict__ fc_w,     // [1,H]
    const float* __restrict__ fc_b,     // [1]
    float* __restrict__ out)            // [B,1]
{
  const int b   = blockIdx.x;
  const int tid = threadIdx.x;
  const int wv  = tid >> 6;   // wave 0..7
  const int l   = tid & 63;
  const int col = l & 15;     // A row / C-col (= tau in ih-GEMM)
  const int grp = l >> 4;     // k-group

  __shared__ __align__(16) _Float16 h_lds[2][HH];
  __shared__ __align__(16) _Float16 xi_st[GROUP][72];  // [tau][chan], +8 pad
  __shared__ float gx_lds[3][HH][17];                  // [gate][hu][tau], pad 17
  __shared__ float h_fin[HH];

  // ---- A-fragments (weights) -> AGPRs, loaded once ----
  h8 whA[3][4];  // g in {r,z,n} x 4 k-tiles (K=128)
  h8 wiA[3][2];  // g x 2 k-tiles (K=64)
  #pragma unroll
  for (int g = 0; g < 3; ++g) {
    const int row = g * HH + wv * 16 + col;
    #pragma unroll
    for (int kt = 0; kt < 4; ++kt) {
      const float* pw = w_hh + (size_t)row * HH + kt * 32 + grp * 8;
      float4 va = *reinterpret_cast<const float4*>(pw);
      float4 vb = *reinterpret_cast<const float4*>(pw + 4);
      h8 f;
      f[0]=(_Float16)va.x; f[1]=(_Float16)va.y; f[2]=(_Float16)va.z; f[3]=(_Float16)va.w;
      f[4]=(_Float16)vb.x; f[5]=(_Float16)vb.y; f[6]=(_Float16)vb.z; f[7]=(_Float16)vb.w;
      whA[g][kt] = f;
    }
    #pragma unroll
    for (int kt = 0; kt < 2; ++kt) {
      const float* pw = w_ih + (size_t)row * II + kt * 32 + grp * 8;
      float4 va = *reinterpret_cast<const float4*>(pw);
      float4 vb = *reinterpret_cast<const float4*>(pw + 4);
      h8 f;
      f[0]=(_Float16)va.x; f[1]=(_Float16)va.y; f[2]=(_Float16)va.z; f[3]=(_Float16)va.w;
      f[4]=(_Float16)vb.x; f[5]=(_Float16)vb.y; f[6]=(_Float16)vb.z; f[7]=(_Float16)vb.w;
      wiA[g][kt] = f;
    }
  }
  #pragma unroll
  for (int g = 0; g < 3; ++g) {
    #pragma unroll
    for (int kt = 0; kt < 4; ++kt) KEEPA(whA[g][kt]);
    #pragma unroll
    for (int kt = 0; kt < 2; ++kt) KEEPA(wiA[g][kt]);
  }

  // bias C-init fragments (hh chains: bR/bZ/bNH; ih-NX chain: bNX)
  f4 bRf, bZf, bNXf, bNHf;
  #pragma unroll
  for (int q = 0; q < 4; ++q) {
    const int hu = wv * 16 + grp * 4 + q;
    bRf[q]  = b_ih[hu]        + b_hh[hu];
    bZf[q]  = b_ih[HH + hu]   + b_hh[HH + hu];
    bNXf[q] = b_ih[2*HH + hu];
    bNHf[q] = b_hh[2*HH + hu];
  }
  f4 zf = {0.f, 0.f, 0.f, 0.f};
  KEEPV(bRf); KEEPV(bZf); KEEPV(bNXf); KEEPV(bNHf); KEEPV(zf);

  // per-lane gate slot
  const int q_l  = col & 3;
  const int hu_l = wv * 16 + grp * 4 + q_l;
  const bool cs1 = (col & 1) != 0;
  const bool cs2 = (col & 2) != 0;
  const bool wlead = (col < 4);
  const int hub = wv * 16 + grp * 4;   // gx-write row base

  // ---- LOCF staging: wave 0 (tid<64), one channel each ----
  const size_t xbase = (size_t)b * SS * II;
  const float* xg = x + xbase;
  const int*   mg = mask + xbase;
  float last = 0.f;
  float x_stg[16];
  int   m_stg[16];
  if (tid < 64) {
    last = x_mean[tid];
    #pragma unroll
    for (int u = 0; u < GROUP; ++u) {
      x_stg[u] = xg[u * II + tid];
      m_stg[u] = mg[u * II + tid];
    }
  }
  float ho = 0.f;  // h[t-1][hu_l], f32

  for (int gq = 0; gq < NG; ++gq) {
    // wave0: LOCF -> xi_st (pre-barrier; consumed by all at tau0 post-barrier)
    if (tid < 64) {
      #pragma unroll
      for (int u = 0; u < GROUP; ++u) {
        last = (m_stg[u] > 0) ? x_stg[u] : last;
        xi_st[u][tid] = pack_f16(last, last).x;
      }
    }

    #pragma unroll
    for (int tau = 0; tau < GROUP; ++tau) {
      const int p = tau & 1;
      if (wlead) h_lds[p][hu_l] = pack_f16(ho, ho).x;
      lds_barrier();  // covers h (and xi_st at tau0)

      if (tau == 0) {
        // prefetch next group's x/mask (stays in flight; vmcnt not drained)
        if (tid < 64 && gq + 1 < NG) {
          const float* xn = xg + (size_t)(gq + 1) * GROUP * II;
          const int*   mn = mg + (size_t)(gq + 1) * GROUP * II;
          #pragma unroll
          for (int u = 0; u < GROUP; ++u) {
            x_stg[u] = xn[u * II + tid];
            m_stg[u] = mn[u * II + tid];
          }
        }
      }

      // gx reads hoisted (tau>=1): latency hides under MFMA issue
      float gxR, gxZ, sNX;
      if (tau != 0) {
        gxR = gx_lds[0][hu_l][tau];
        gxZ = gx_lds[1][hu_l][tau];
        sNX = gx_lds[2][hu_l][tau];
      }

      h8 hB[4];
      #pragma unroll
      for (int kt = 0; kt < 4; ++kt)
        hB[kt] = *reinterpret_cast<const h8*>(&h_lds[p][kt * 32 + grp * 8]);

      // 12 hh MFMAs, chains bit-identical to R10/R12: {bias -> hh0..3}
      f4 aR  = mfma_first(whA[0][0], hB[0], bRf);
      f4 aZ  = mfma_first(whA[1][0], hB[0], bZf);
      f4 aNH = mfma_first(whA[2][0], hB[0], bNHf);
      #pragma unroll
      for (int kt = 1; kt < 4; ++kt) {
        mfma_acc(aR,  whA[0][kt], hB[kt]);
        mfma_acc(aZ,  whA[1][kt], hB[kt]);
        mfma_acc(aNH, whA[2][kt], hB[kt]);
      }

      if (tau == 0) {
        // ih-GEMM merged in: 6 MFMAs fill the pipe; chains identical to R12
        h8 xB0 = *reinterpret_cast<const h8*>(&xi_st[col][grp * 8]);
        h8 xB1 = *reinterpret_cast<const h8*>(&xi_st[col][32 + grp * 8]);
        f4 gR  = mfma_first(wiA[0][0], xB0, zf);
        f4 gZ  = mfma_first(wiA[1][0], xB0, zf);
        f4 gNX = mfma_first(wiA[2][0], xB0, bNXf);
        mfma_acc(gR,  wiA[0][1], xB1);
        mfma_acc(gZ,  wiA[1][1], xB1);
        mfma_acc(gNX, wiA[2][1], xB1);
        asm volatile("s_nop 7\n\ts_nop 7");
        __builtin_amdgcn_sched_barrier(0);
        // gx writes: [gate][hu][tau=col] b32, <=2-way banked; intra-wave data
        #pragma unroll
        for (int q = 0; q < 4; ++q) {
          gx_lds[0][hub + q][col] = gR[q];
          gx_lds[1][hub + q][col] = gZ[q];
          gx_lds[2][hub + q][col] = gNX[q];
        }
        asm volatile("s_waitcnt lgkmcnt(0)" ::: "memory");
        __builtin_amdgcn_sched_barrier(0);
        gxR = gx_lds[0][hu_l][0];
        gxZ = gx_lds[1][hu_l][0];
        sNX = gx_lds[2][hu_l][0];
      } else {
        asm volatile("s_nop 7\n\ts_nop 7");
        __builtin_amdgcn_sched_barrier(0);
      }

      // dedup selects (masks loop-invariant) + gate math (unchanged since R8)
      const float sR  = (cs2 ? (cs1 ? aR[3]  : aR[2])  : (cs1 ? aR[1]  : aR[0]))  + gxR;
      const float sZ  = (cs2 ? (cs1 ? aZ[3]  : aZ[2])  : (cs1 ? aZ[1]  : aZ[0]))  + gxZ;
      const float sNH =  cs2 ? (cs1 ? aNH[3] : aNH[2]) : (cs1 ? aNH[1] : aNH[0]);

      float r = fast_rcp(1.f + __expf(-sR));
      float z = fast_rcp(1.f + __expf(-sZ));
      float a = sNX + r * sNH;
      float n = 1.f - 2.f * fast_rcp(__expf(2.f * a) + 1.f);
      ho = n + z * (ho - n);
    }
  }

  // publish final h (f32)
  if (wlead) h_fin[hu_l] = ho;
  __syncthreads();

  // BN (eval) + FC, reduced by wave 0
  if (tid < 64) {
    float pacc = 0.f;
    #pragma unroll
    for (int q = 0; q < 2; ++q) {
      const int k = tid + q * 64;
      const float hv2 = h_fin[k];
      const float nrm = (hv2 - bn_mean[k]) * rsqrtf(bn_var[k] + 1e-5f) * bn_gamma[k] + bn_beta[k];
      pacc += nrm * fc_w[k];
    }
    #pragma unroll
    for (int off = 32; off > 0; off >>= 1) pacc += __shfl_down(pacc, off);
    if (tid == 0) out[b] = pacc + fc_b[0];
  }
}

extern "C" void kernel_launch(void* const* d_in, const int* in_sizes, int n_in,
                              void* d_out, int out_size, void* d_ws, size_t ws_size,
                              hipStream_t stream) {
  const float* x        = (const float*)d_in[0];
  const int*   mask     = (const int*)  d_in[1];
  // d_in[2] = delta (unused by reference forward)
  const float* x_mean   = (const float*)d_in[3];
  const float* w_ih     = (const float*)d_in[4];
  const float* w_hh     = (const float*)d_in[5];
  const float* b_ih     = (const float*)d_in[6];
  const float* b_hh     = (const float*)d_in[7];
  const float* bn_gamma = (const float*)d_in[8];
  const float* bn_beta  = (const float*)d_in[9];
  const float* bn_mean  = (const float*)d_in[10];
  const float* bn_var   = (const float*)d_in[11];
  const float* fc_w     = (const float*)d_in[12];
  const float* fc_b     = (const float*)d_in[13];
  float* out = (float*)d_out;

  gru_fused<<<dim3(BB), dim3(512), 0, stream>>>(
      x, mask, x_mean, w_ih, w_hh, b_ih, b_hh,
      bn_gamma, bn_beta, bn_mean, bn_var, fc_w, fc_b, out);
}